// Round 16
// baseline (214.552 us; speedup 1.0000x reference)
//
#include <hip/hip_runtime.h>
#include <hip/hip_fp16.h>

#define B_SZ  512
#define S_LEN 512
#define D_IN  64
#define H_DIM 32
#define KPIPE 16                   // steps per super-step (ring depth)
#define NSUPER (S_LEN / KPIPE)     // 32

typedef _Float16 h2 __attribute__((ext_vector_type(2)));

__device__ __forceinline__ float fsig(float x) {
    float e = __builtin_amdgcn_exp2f(x * -1.44269504088896340736f);
    return __builtin_amdgcn_rcpf(1.0f + e);
}
__device__ __forceinline__ float ftanh(float x) {
    float e = __builtin_amdgcn_exp2f(x * -2.88539008177792681472f);
    return __builtin_fmaf(2.0f, __builtin_amdgcn_rcpf(1.0f + e), -1.0f);
}

#if __has_builtin(__builtin_amdgcn_fdot2)
__device__ __forceinline__ float fdot2(h2 a, h2 b, float c) {
    return __builtin_amdgcn_fdot2(a, b, c, false);   // v_dot2_f32_f16
}
#else
__device__ __forceinline__ float fdot2(h2 a, h2 b, float c) {
    return __builtin_fmaf((float)a[1], (float)b[1],
           __builtin_fmaf((float)a[0], (float)b[0], c));
}
#endif

__device__ __forceinline__ h2 u2h2(unsigned int u) { return __builtin_bit_cast(h2, u); }
__device__ __forceinline__ unsigned int pk16(float x, float y) {
    unsigned int lo = __half_as_ushort(__float2half_rn(x));
    unsigned int hi = __half_as_ushort(__float2half_rn(y));
    return lo | (hi << 16);
}

// Exchange with lane^1 on the VALU: v_mov_b32 dpp quad_perm:[1,0,3,2].
__device__ __forceinline__ float dpp_swap1(float x) {
    return __builtin_bit_cast(float, __builtin_amdgcn_mov_dpp(
        __builtin_bit_cast(int, x), 0xB1, 0xF, 0xF, false));
}

// Compiler-only memory fence (no instruction, doesn't drain vmcnt).
#define LDS_ORDER() asm volatile("" ::: "memory")
// LDS-drain + compiler fence, WITHOUT vmcnt drain.
#define LGKM_FENCE() asm volatile("s_waitcnt lgkmcnt(0)" ::: "memory")
// VMEM-drain (x staging loads), lgkm untouched.
#define VM_FENCE()   asm volatile("s_waitcnt vmcnt(0)" ::: "memory")

// ---------------------------------------------------------------------------
// SINGLE fused kernel, THREE-WAVE specialization (R15 structure).
// block = 192 thr = 3 waves = ONE batch row; 512 blocks = 1536 waves (6/CU).
//   wave2 = gx producer (prio 0): stages x one super-step ahead, computes
//           gx block s+1 into ring gxbuf[(s+1)&1].
//   wave0 = layer 0 (prio 1): act -> h0 ring -> Whh0 dots.
//   wave1 = layer 1 + FC (prio 1): consumes h0 block s-1; wi1 and wh1 dots
//           now in SEPARATE accumulators (dep chain 16 -> 8).
// KPIPE=16: one s_barrier per 16 steps (33/wave vs 65 in R15).
// ---------------------------------------------------------------------------
__global__ __launch_bounds__(192, 1) void lstm_scan_kernel(
    const float* __restrict__ x,
    const float* __restrict__ Wih0,
    const float* __restrict__ Whh0,
    const float* __restrict__ bih0,
    const float* __restrict__ bhh0,
    const float* __restrict__ Wih1,
    const float* __restrict__ Whh1,
    const float* __restrict__ bih1,
    const float* __restrict__ bhh1,
    const float* __restrict__ Wfc,
    const float* __restrict__ bfc,
    float* __restrict__ out)
{
    const int tid  = threadIdx.x;
    const int lane = tid & 63;
    const int j    = lane >> 1;
    const int p    = lane & 1;
    const int b    = blockIdx.x;
    const int rA   = p ? (32 + j) : j;    // gateA row: p=0 -> i_j, p=1 -> f_j
    const int rB   = rA + 64;             // gateB row: p=0 -> g_j, p=1 -> o_j

    __shared__ unsigned short h0buf[2][KPIPE][32];   // wave0 -> wave1
    __shared__ unsigned short h1sm[32];              // wave1-private
    __shared__ unsigned int   xbuf[KPIPE][32];       // wave2-private (x fp16x2)
    __shared__ unsigned int   gxbuf[2][KPIPE][64];   // wave2 -> wave0

    // gateA (i or f): sigmoid. gateB: p=0 -> tanh (g), p=1 -> sigmoid (o).
    const float sclB = p ? -1.44269504088896340736f : -2.88539008177792681472f;
    const float mulB = p ?  1.0f : 2.0f;
    const float addB = p ?  0.0f : -1.0f;

    if (tid < 64) {
        // ================= WAVE 0 : layer 0 =================
        __builtin_amdgcn_s_setprio(1);
        unsigned int wh0A[16], wh0B[16];
        #pragma unroll
        for (int k4 = 0; k4 < 8; ++k4) {
            float4 v;
            v = reinterpret_cast<const float4*>(Whh0 + rA * 32)[k4];
            wh0A[2*k4+0] = pk16(v.x, v.y);  wh0A[2*k4+1] = pk16(v.z, v.w);
            v = reinterpret_cast<const float4*>(Whh0 + rB * 32)[k4];
            wh0B[2*k4+0] = pk16(v.x, v.y);  wh0B[2*k4+1] = pk16(v.z, v.w);
        }
        #pragma unroll
        for (int k = 0; k < 16; ++k)
            asm volatile("" : "+v"(wh0A[k]), "+v"(wh0B[k]));

        h2 h0p[16];
        #pragma unroll
        for (int k = 0; k < 16; ++k) h0p[k] = (h2){0, 0};
        float c0 = 0.f;
        float zA = 0.f, zB = 0.f;         // Whh0.h0(t-1); 0 at t=0

        LGKM_FENCE();
        __builtin_amdgcn_s_barrier();     // prologue: gx block 0 ready

        for (int s = 0; s < NSUPER; ++s) {
            // fetch this super-step's 16 gx values (written in s-1)
            unsigned int gxr[KPIPE];
            LDS_ORDER();
            #pragma unroll
            for (int u = 0; u < KPIPE; ++u) gxr[u] = gxbuf[s & 1][u][lane];
            LDS_ORDER();

            unsigned short (*slot)[32] = h0buf[s & 1];
            #pragma unroll
            for (int u = 0; u < KPIPE; ++u) {
                h2 g = u2h2(gxr[u]);
                const float aA = zA + (float)g[0];
                const float aB = zB + (float)g[1];

                // act chain + DPP combine + cell + h0(t)
                const float vA = fsig(aA);
                float vB;
                { float e = __builtin_amdgcn_exp2f(sclB * aB);
                  vB = __builtin_fmaf(mulB, __builtin_amdgcn_rcpf(1.0f + e), addB); }
                const float nA = dpp_swap1(vA);
                const float nB = dpp_swap1(vB);
                const float iv = p ? nA : vA;
                const float fv = p ? vA : nA;
                const float gv = p ? nB : vB;
                const float ov = p ? vB : nB;
                c0 = __builtin_fmaf(fv, c0, iv * gv);
                const float h0 = ov * ftanh(c0);

                // publish h0(t); read back own packed copy
                LDS_ORDER();
                slot[u][j] = (unsigned short)__half_as_ushort(__float2half_rn(h0));
                LDS_ORDER();
                {
                    const uint4* hp = reinterpret_cast<const uint4*>(&slot[u][0]);
                    uint4 a0 = hp[0], a1 = hp[1], a2 = hp[2], a3 = hp[3];
                    h0p[ 0]=u2h2(a0.x); h0p[ 1]=u2h2(a0.y); h0p[ 2]=u2h2(a0.z); h0p[ 3]=u2h2(a0.w);
                    h0p[ 4]=u2h2(a1.x); h0p[ 5]=u2h2(a1.y); h0p[ 6]=u2h2(a1.z); h0p[ 7]=u2h2(a1.w);
                    h0p[ 8]=u2h2(a2.x); h0p[ 9]=u2h2(a2.y); h0p[10]=u2h2(a2.z); h0p[11]=u2h2(a2.w);
                    h0p[12]=u2h2(a3.x); h0p[13]=u2h2(a3.y); h0p[14]=u2h2(a3.z); h0p[15]=u2h2(a3.w);
                }

                // Whh0 . h0(t) -> carried into step t+1
                float zA0 = 0.f, zA1 = 0.f, zB0 = 0.f, zB1 = 0.f;
                #pragma unroll
                for (int k = 0; k < 16; k += 2) {
                    zA0 = fdot2(h0p[k],   u2h2(wh0A[k]),   zA0);
                    zA1 = fdot2(h0p[k+1], u2h2(wh0A[k+1]), zA1);
                    zB0 = fdot2(h0p[k],   u2h2(wh0B[k]),   zB0);
                    zB1 = fdot2(h0p[k+1], u2h2(wh0B[k+1]), zB1);
                }
                zA = zA0 + zA1;  zB = zB0 + zB1;
            }
            LGKM_FENCE();
            __builtin_amdgcn_s_barrier();
        }
    } else if (tid < 128) {
        // ================= WAVE 1 : layer 1 + FC =================
        __builtin_amdgcn_s_setprio(1);
        unsigned int wi1A[16], wi1B[16], wh1A[16], wh1B[16];
        #pragma unroll
        for (int k4 = 0; k4 < 8; ++k4) {
            float4 v;
            v = reinterpret_cast<const float4*>(Wih1 + rA * 32)[k4];
            wi1A[2*k4+0] = pk16(v.x, v.y);  wi1A[2*k4+1] = pk16(v.z, v.w);
            v = reinterpret_cast<const float4*>(Wih1 + rB * 32)[k4];
            wi1B[2*k4+0] = pk16(v.x, v.y);  wi1B[2*k4+1] = pk16(v.z, v.w);
            v = reinterpret_cast<const float4*>(Whh1 + rA * 32)[k4];
            wh1A[2*k4+0] = pk16(v.x, v.y);  wh1A[2*k4+1] = pk16(v.z, v.w);
            v = reinterpret_cast<const float4*>(Whh1 + rB * 32)[k4];
            wh1B[2*k4+0] = pk16(v.x, v.y);  wh1B[2*k4+1] = pk16(v.z, v.w);
        }
        #pragma unroll
        for (int k = 0; k < 16; ++k)
            asm volatile("" : "+v"(wi1A[k]), "+v"(wi1B[k]),
                              "+v"(wh1A[k]), "+v"(wh1B[k]));

        const float b1A = bih1[rA] + bhh1[rA];
        const float b1B = bih1[rB] + bhh1[rB];

        h2 h1p[16];
        #pragma unroll
        for (int k = 0; k < 16; ++k) h1p[k] = (h2){0, 0};   // h1(-1) = 0
        float c1 = 0.f;
        float h1last = 0.f;

        auto consumeK = [&](const unsigned short (*slot)[32]) {
            uint4 d0, d1, d2, d3;
            {
                const uint4* hq = reinterpret_cast<const uint4*>(&slot[0][0]);
                d0 = hq[0]; d1 = hq[1]; d2 = hq[2]; d3 = hq[3];
            }
            #pragma unroll
            for (int u = 0; u < KPIPE; ++u) {
                h2 h0q[16];
                h0q[ 0]=u2h2(d0.x); h0q[ 1]=u2h2(d0.y); h0q[ 2]=u2h2(d0.z); h0q[ 3]=u2h2(d0.w);
                h0q[ 4]=u2h2(d1.x); h0q[ 5]=u2h2(d1.y); h0q[ 6]=u2h2(d1.z); h0q[ 7]=u2h2(d1.w);
                h0q[ 8]=u2h2(d2.x); h0q[ 9]=u2h2(d2.y); h0q[10]=u2h2(d2.z); h0q[11]=u2h2(d2.w);
                h0q[12]=u2h2(d3.x); h0q[13]=u2h2(d3.y); h0q[14]=u2h2(d3.z); h0q[15]=u2h2(d3.w);
                if (u + 1 < KPIPE) {
                    const uint4* hq = reinterpret_cast<const uint4*>(&slot[u + 1][0]);
                    d0 = hq[0]; d1 = hq[1]; d2 = hq[2]; d3 = hq[3];
                }

                // wi1 dots (q accums) cover the h1p RT; wh1 dots in SEPARATE
                // s accums -> post-RT dep chain is 8, not 16.
                float qA0 = b1A, qA1 = 0.f, qB0 = b1B, qB1 = 0.f;
                float sA0 = 0.f, sA1 = 0.f, sB0 = 0.f, sB1 = 0.f;
                #pragma unroll
                for (int k = 0; k < 16; k += 2) {
                    qA0 = fdot2(h0q[k],   u2h2(wi1A[k]),   qA0);
                    qA1 = fdot2(h0q[k+1], u2h2(wi1A[k+1]), qA1);
                    qB0 = fdot2(h0q[k],   u2h2(wi1B[k]),   qB0);
                    qB1 = fdot2(h0q[k+1], u2h2(wi1B[k+1]), qB1);
                }
                #pragma unroll
                for (int k = 0; k < 16; k += 2) {
                    sA0 = fdot2(h1p[k],   u2h2(wh1A[k]),   sA0);
                    sA1 = fdot2(h1p[k+1], u2h2(wh1A[k+1]), sA1);
                    sB0 = fdot2(h1p[k],   u2h2(wh1B[k]),   sB0);
                    sB1 = fdot2(h1p[k+1], u2h2(wh1B[k+1]), sB1);
                }
                const float qA = (qA0 + qA1) + (sA0 + sA1);
                const float qB = (qB0 + qB1) + (sB0 + sB1);

                const float wA = fsig(qA);
                float wB;
                { float e = __builtin_amdgcn_exp2f(sclB * qB);
                  wB = __builtin_fmaf(mulB, __builtin_amdgcn_rcpf(1.0f + e), addB); }
                const float mA = dpp_swap1(wA);
                const float mB = dpp_swap1(wB);
                const float iv1 = p ? mA : wA;
                const float fv1 = p ? wA : mA;
                const float gv1 = p ? mB : wB;
                const float ov1 = p ? wB : mB;
                c1 = __builtin_fmaf(fv1, c1, iv1 * gv1);
                const float h1 = ov1 * ftanh(c1);
                h1last = h1;

                LDS_ORDER();
                h1sm[j] = (unsigned short)__half_as_ushort(__float2half_rn(h1));
                LDS_ORDER();
                {
                    const uint4* hp = reinterpret_cast<const uint4*>(h1sm);
                    uint4 a0 = hp[0], a1 = hp[1], a2 = hp[2], a3 = hp[3];
                    h1p[ 0]=u2h2(a0.x); h1p[ 1]=u2h2(a0.y); h1p[ 2]=u2h2(a0.z); h1p[ 3]=u2h2(a0.w);
                    h1p[ 4]=u2h2(a1.x); h1p[ 5]=u2h2(a1.y); h1p[ 6]=u2h2(a1.z); h1p[ 7]=u2h2(a1.w);
                    h1p[ 8]=u2h2(a2.x); h1p[ 9]=u2h2(a2.y); h1p[10]=u2h2(a2.z); h1p[11]=u2h2(a2.w);
                    h1p[12]=u2h2(a3.x); h1p[13]=u2h2(a3.y); h1p[14]=u2h2(a3.z); h1p[15]=u2h2(a3.w);
                }
            }
        };

        LGKM_FENCE();
        __builtin_amdgcn_s_barrier();     // prologue
        for (int s = 0; s < NSUPER; ++s) {
            if (s > 0) consumeK(h0buf[(s - 1) & 1]);
            LGKM_FENCE();
            __builtin_amdgcn_s_barrier();
        }
        consumeK(h0buf[(NSUPER - 1) & 1]);

        // FC: pair lanes both hold h1[j]; mask odd lanes, 64-lane reduce
        float pFC = p ? 0.0f : h1last * Wfc[j];
        pFC += __shfl_xor(pFC, 32);
        pFC += __shfl_xor(pFC, 16);
        pFC += __shfl_xor(pFC, 8);
        pFC += __shfl_xor(pFC, 4);
        pFC += __shfl_xor(pFC, 2);
        pFC += __shfl_xor(pFC, 1);
        if (lane == 0) out[b] = pFC + bfc[0];
    } else {
        // ================= WAVE 2 : gx producer (prio 0) ===================
        unsigned int wi0A[32], wi0B[32];
        #pragma unroll
        for (int k4 = 0; k4 < 16; ++k4) {
            float4 v;
            v = reinterpret_cast<const float4*>(Wih0 + rA * 64)[k4];
            wi0A[2*k4+0] = pk16(v.x, v.y);  wi0A[2*k4+1] = pk16(v.z, v.w);
            v = reinterpret_cast<const float4*>(Wih0 + rB * 64)[k4];
            wi0B[2*k4+0] = pk16(v.x, v.y);  wi0B[2*k4+1] = pk16(v.z, v.w);
        }
        #pragma unroll
        for (int k = 0; k < 32; ++k)
            asm volatile("" : "+v"(wi0A[k]), "+v"(wi0B[k]));

        const float b0A = bih0[rA] + bhh0[rA];
        const float b0B = bih0[rB] + bhh0[rB];

        // x staging: lane owns 16 consecutive floats of each 1024-float block.
        const float* xrow = x + (size_t)b * S_LEN * 64;
        const int tsub = lane >> 2;          // sub-step within block
        const int kq   = (lane & 3) * 8;     // u32 slot base

        float4 xr0, xr1, xr2, xr3;
        auto issue_loads = [&](int blk) {
            const float* base = xrow + (size_t)blk * (KPIPE * 64) + lane * 16;
            xr0 = reinterpret_cast<const float4*>(base)[0];
            xr1 = reinterpret_cast<const float4*>(base + 4)[0];
            xr2 = reinterpret_cast<const float4*>(base + 8)[0];
            xr3 = reinterpret_cast<const float4*>(base + 12)[0];
        };
        auto stage = [&]() {
            uint4 w0, w1;
            w0.x = pk16(xr0.x, xr0.y);  w0.y = pk16(xr0.z, xr0.w);
            w0.z = pk16(xr1.x, xr1.y);  w0.w = pk16(xr1.z, xr1.w);
            w1.x = pk16(xr2.x, xr2.y);  w1.y = pk16(xr2.z, xr2.w);
            w1.z = pk16(xr3.x, xr3.y);  w1.w = pk16(xr3.z, xr3.w);
            LDS_ORDER();
            *reinterpret_cast<uint4*>(&xbuf[tsub][kq])     = w0;
            *reinterpret_cast<uint4*>(&xbuf[tsub][kq + 4]) = w1;
            LDS_ORDER();
        };
        auto compute_block = [&](unsigned int (*dst)[64]) {
            #pragma unroll
            for (int u = 0; u < KPIPE; ++u) {
                uint4 xv[8];
                #pragma unroll
                for (int q = 0; q < 8; ++q)
                    xv[q] = reinterpret_cast<const uint4*>(&xbuf[u][0])[q];
                float gA0 = b0A, gA1 = 0.f, gB0 = b0B, gB1 = 0.f;
                #pragma unroll
                for (int q = 0; q < 8; ++q) {
                    gA0 = fdot2(u2h2(xv[q].x), u2h2(wi0A[4*q+0]), gA0);
                    gA1 = fdot2(u2h2(xv[q].y), u2h2(wi0A[4*q+1]), gA1);
                    gA0 = fdot2(u2h2(xv[q].z), u2h2(wi0A[4*q+2]), gA0);
                    gA1 = fdot2(u2h2(xv[q].w), u2h2(wi0A[4*q+3]), gA1);
                    gB0 = fdot2(u2h2(xv[q].x), u2h2(wi0B[4*q+0]), gB0);
                    gB1 = fdot2(u2h2(xv[q].y), u2h2(wi0B[4*q+1]), gB1);
                    gB0 = fdot2(u2h2(xv[q].z), u2h2(wi0B[4*q+2]), gB0);
                    gB1 = fdot2(u2h2(xv[q].w), u2h2(wi0B[4*q+3]), gB1);
                }
                LDS_ORDER();
                dst[u][lane] = pk16(gA0 + gA1, gB0 + gB1);
                LDS_ORDER();
            }
        };

        // prologue: block 0 sync -> gxbuf[0]; issue block 1 loads
        issue_loads(0);
        VM_FENCE();
        stage();
        compute_block(gxbuf[0]);
        issue_loads(1 < NSUPER ? 1 : 0);

        LGKM_FENCE();
        __builtin_amdgcn_s_barrier();     // prologue

        for (int s = 0; s < NSUPER; ++s) {
            VM_FENCE();                   // block s+1 landed
            stage();
            compute_block(gxbuf[(s + 1) & 1]);
            issue_loads((s + 2 < NSUPER) ? (s + 2) : (NSUPER - 1));
            LGKM_FENCE();
            __builtin_amdgcn_s_barrier();
        }
    }
}

extern "C" void kernel_launch(void* const* d_in, const int* in_sizes, int n_in,
                              void* d_out, int out_size, void* d_ws, size_t ws_size,
                              hipStream_t stream) {
    (void)in_sizes; (void)n_in; (void)out_size; (void)d_ws; (void)ws_size;
    const float* x    = (const float*)d_in[0];
    const float* Wih0 = (const float*)d_in[1];
    const float* Whh0 = (const float*)d_in[2];
    const float* bih0 = (const float*)d_in[3];
    const float* bhh0 = (const float*)d_in[4];
    const float* Wih1 = (const float*)d_in[5];
    const float* Whh1 = (const float*)d_in[6];
    const float* bih1 = (const float*)d_in[7];
    const float* bhh1 = (const float*)d_in[8];
    const float* Wfc  = (const float*)d_in[9];
    const float* bfc  = (const float*)d_in[10];
    float* out = (float*)d_out;

    hipLaunchKernelGGL(lstm_scan_kernel, dim3(B_SZ), dim3(192), 0, stream,
                       x, Wih0, Whh0, bih0, bhh0, Wih1, Whh1, bih1, bhh1,
                       Wfc, bfc, out);
}

// Round 17
// 204.822 us; speedup vs baseline: 1.0475x; 1.0475x over previous
//
#include <hip/hip_runtime.h>
#include <hip/hip_fp16.h>

#define B_SZ  512
#define S_LEN 512
#define D_IN  64
#define H_DIM 32
#define KPIPE 8                    // steps per super-step (ring depth)
#define NSUPER (S_LEN / KPIPE)     // 64

typedef _Float16 h2 __attribute__((ext_vector_type(2)));

__device__ __forceinline__ float fsig(float x) {
    float e = __builtin_amdgcn_exp2f(x * -1.44269504088896340736f);
    return __builtin_amdgcn_rcpf(1.0f + e);
}
__device__ __forceinline__ float ftanh(float x) {
    float e = __builtin_amdgcn_exp2f(x * -2.88539008177792681472f);
    return __builtin_fmaf(2.0f, __builtin_amdgcn_rcpf(1.0f + e), -1.0f);
}

#if __has_builtin(__builtin_amdgcn_fdot2)
__device__ __forceinline__ float fdot2(h2 a, h2 b, float c) {
    return __builtin_amdgcn_fdot2(a, b, c, false);   // v_dot2_f32_f16
}
#else
__device__ __forceinline__ float fdot2(h2 a, h2 b, float c) {
    return __builtin_fmaf((float)a[1], (float)b[1],
           __builtin_fmaf((float)a[0], (float)b[0], c));
}
#endif

__device__ __forceinline__ h2 u2h2(unsigned int u) { return __builtin_bit_cast(h2, u); }
__device__ __forceinline__ unsigned int pk16(float x, float y) {
    unsigned int lo = __half_as_ushort(__float2half_rn(x));
    unsigned int hi = __half_as_ushort(__float2half_rn(y));
    return lo | (hi << 16);
}

// Exchange with lane^1 on the VALU: v_mov_b32 dpp quad_perm:[1,0,3,2].
__device__ __forceinline__ float dpp_swap1(float x) {
    return __builtin_bit_cast(float, __builtin_amdgcn_mov_dpp(
        __builtin_bit_cast(int, x), 0xB1, 0xF, 0xF, false));
}

// Compiler-only memory fence (no instruction, doesn't drain vmcnt).
#define LDS_ORDER() asm volatile("" ::: "memory")
// LDS-drain + compiler fence, WITHOUT vmcnt drain.
#define LGKM_FENCE() asm volatile("s_waitcnt lgkmcnt(0)" ::: "memory")
// VMEM-drain (x staging loads), lgkm untouched.
#define VM_FENCE()   asm volatile("s_waitcnt vmcnt(0)" ::: "memory")

// ---------------------------------------------------------------------------
// SINGLE fused kernel, THREE-WAVE specialization (R15 structure, verbatim,
// plus ONE change: wave1's wi1/wh1 dots use separate accumulators so the
// post-LDS-read dependency chain is 8 fdot2, not 16).
// block = 192 thr = 3 waves = ONE batch row; 512 blocks = 1536 waves (6/CU).
//   wave2 = gx producer: stages x one super-step ahead, computes gx block
//           s+1 into ring gxbuf[(s+1)&1].
//   wave0 = layer 0: act -> h0 ring -> Whh0 dots.
//   wave1 = layer 1 + FC: consumes h0 block s-1.
// 65 s_barriers per wave, lgkmcnt-only drains (vmcnt stays in flight).
// (R16 post-mortem: KPIPE=16 staging layout caused 16-way LDS write
// conflicts + 64B/lane load stride; setprio on lockstep waves is harmful.
// All three reverted.)
// ---------------------------------------------------------------------------
__global__ __launch_bounds__(192, 1) void lstm_scan_kernel(
    const float* __restrict__ x,
    const float* __restrict__ Wih0,
    const float* __restrict__ Whh0,
    const float* __restrict__ bih0,
    const float* __restrict__ bhh0,
    const float* __restrict__ Wih1,
    const float* __restrict__ Whh1,
    const float* __restrict__ bih1,
    const float* __restrict__ bhh1,
    const float* __restrict__ Wfc,
    const float* __restrict__ bfc,
    float* __restrict__ out)
{
    const int tid  = threadIdx.x;
    const int lane = tid & 63;
    const int j    = lane >> 1;
    const int p    = lane & 1;
    const int b    = blockIdx.x;
    const int rA   = p ? (32 + j) : j;    // gateA row: p=0 -> i_j, p=1 -> f_j
    const int rB   = rA + 64;             // gateB row: p=0 -> g_j, p=1 -> o_j

    __shared__ unsigned short h0buf[2][KPIPE][32];   // wave0 -> wave1
    __shared__ unsigned short h1sm[32];              // wave1-private
    __shared__ unsigned int   xbuf[KPIPE][32];       // wave2-private (x fp16x2)
    __shared__ unsigned int   gxbuf[2][KPIPE][64];   // wave2 -> wave0

    // gateA (i or f): sigmoid. gateB: p=0 -> tanh (g), p=1 -> sigmoid (o).
    const float sclB = p ? -1.44269504088896340736f : -2.88539008177792681472f;
    const float mulB = p ?  1.0f : 2.0f;
    const float addB = p ?  0.0f : -1.0f;

    if (tid < 64) {
        // ================= WAVE 0 : layer 0 (R15-identical) ================
        unsigned int wh0A[16], wh0B[16];
        #pragma unroll
        for (int k4 = 0; k4 < 8; ++k4) {
            float4 v;
            v = reinterpret_cast<const float4*>(Whh0 + rA * 32)[k4];
            wh0A[2*k4+0] = pk16(v.x, v.y);  wh0A[2*k4+1] = pk16(v.z, v.w);
            v = reinterpret_cast<const float4*>(Whh0 + rB * 32)[k4];
            wh0B[2*k4+0] = pk16(v.x, v.y);  wh0B[2*k4+1] = pk16(v.z, v.w);
        }
        #pragma unroll
        for (int k = 0; k < 16; ++k)
            asm volatile("" : "+v"(wh0A[k]), "+v"(wh0B[k]));

        h2 h0p[16];
        #pragma unroll
        for (int k = 0; k < 16; ++k) h0p[k] = (h2){0, 0};
        float c0 = 0.f;
        float zA = 0.f, zB = 0.f;         // Whh0.h0(t-1); 0 at t=0

        LGKM_FENCE();
        __builtin_amdgcn_s_barrier();     // prologue: gx block 0 ready

        for (int s = 0; s < NSUPER; ++s) {
            // fetch this super-step's 8 gx values (block fully written in s-1)
            unsigned int gxr[KPIPE];
            LDS_ORDER();
            #pragma unroll
            for (int u = 0; u < KPIPE; ++u) gxr[u] = gxbuf[s & 1][u][lane];
            LDS_ORDER();

            unsigned short (*slot)[32] = h0buf[s & 1];
            #pragma unroll
            for (int u = 0; u < KPIPE; ++u) {
                h2 g = u2h2(gxr[u]);
                const float aA = zA + (float)g[0];
                const float aB = zB + (float)g[1];

                // act chain + DPP combine + cell + h0(t)
                const float vA = fsig(aA);
                float vB;
                { float e = __builtin_amdgcn_exp2f(sclB * aB);
                  vB = __builtin_fmaf(mulB, __builtin_amdgcn_rcpf(1.0f + e), addB); }
                const float nA = dpp_swap1(vA);
                const float nB = dpp_swap1(vB);
                const float iv = p ? nA : vA;
                const float fv = p ? vA : nA;
                const float gv = p ? nB : vB;
                const float ov = p ? vB : nB;
                c0 = __builtin_fmaf(fv, c0, iv * gv);
                const float h0 = ov * ftanh(c0);

                // publish h0(t); read back own packed copy
                LDS_ORDER();
                slot[u][j] = (unsigned short)__half_as_ushort(__float2half_rn(h0));
                LDS_ORDER();
                {
                    const uint4* hp = reinterpret_cast<const uint4*>(&slot[u][0]);
                    uint4 a0 = hp[0], a1 = hp[1], a2 = hp[2], a3 = hp[3];
                    h0p[ 0]=u2h2(a0.x); h0p[ 1]=u2h2(a0.y); h0p[ 2]=u2h2(a0.z); h0p[ 3]=u2h2(a0.w);
                    h0p[ 4]=u2h2(a1.x); h0p[ 5]=u2h2(a1.y); h0p[ 6]=u2h2(a1.z); h0p[ 7]=u2h2(a1.w);
                    h0p[ 8]=u2h2(a2.x); h0p[ 9]=u2h2(a2.y); h0p[10]=u2h2(a2.z); h0p[11]=u2h2(a2.w);
                    h0p[12]=u2h2(a3.x); h0p[13]=u2h2(a3.y); h0p[14]=u2h2(a3.z); h0p[15]=u2h2(a3.w);
                }

                // Whh0 . h0(t) -> carried into step t+1
                float zA0 = 0.f, zA1 = 0.f, zB0 = 0.f, zB1 = 0.f;
                #pragma unroll
                for (int k = 0; k < 16; k += 2) {
                    zA0 = fdot2(h0p[k],   u2h2(wh0A[k]),   zA0);
                    zA1 = fdot2(h0p[k+1], u2h2(wh0A[k+1]), zA1);
                    zB0 = fdot2(h0p[k],   u2h2(wh0B[k]),   zB0);
                    zB1 = fdot2(h0p[k+1], u2h2(wh0B[k+1]), zB1);
                }
                zA = zA0 + zA1;  zB = zB0 + zB1;
            }
            LGKM_FENCE();
            __builtin_amdgcn_s_barrier();
        }
    } else if (tid < 128) {
        // ========== WAVE 1 : layer 1 + FC (R15 + chain-split ONLY) =========
        unsigned int wi1A[16], wi1B[16], wh1A[16], wh1B[16];
        #pragma unroll
        for (int k4 = 0; k4 < 8; ++k4) {
            float4 v;
            v = reinterpret_cast<const float4*>(Wih1 + rA * 32)[k4];
            wi1A[2*k4+0] = pk16(v.x, v.y);  wi1A[2*k4+1] = pk16(v.z, v.w);
            v = reinterpret_cast<const float4*>(Wih1 + rB * 32)[k4];
            wi1B[2*k4+0] = pk16(v.x, v.y);  wi1B[2*k4+1] = pk16(v.z, v.w);
            v = reinterpret_cast<const float4*>(Whh1 + rA * 32)[k4];
            wh1A[2*k4+0] = pk16(v.x, v.y);  wh1A[2*k4+1] = pk16(v.z, v.w);
            v = reinterpret_cast<const float4*>(Whh1 + rB * 32)[k4];
            wh1B[2*k4+0] = pk16(v.x, v.y);  wh1B[2*k4+1] = pk16(v.z, v.w);
        }
        #pragma unroll
        for (int k = 0; k < 16; ++k)
            asm volatile("" : "+v"(wi1A[k]), "+v"(wi1B[k]),
                              "+v"(wh1A[k]), "+v"(wh1B[k]));

        const float b1A = bih1[rA] + bhh1[rA];
        const float b1B = bih1[rB] + bhh1[rB];

        h2 h1p[16];
        #pragma unroll
        for (int k = 0; k < 16; ++k) h1p[k] = (h2){0, 0};   // h1(-1) = 0
        float c1 = 0.f;
        float h1last = 0.f;

        auto consume8 = [&](const unsigned short (*slot)[32]) {
            uint4 d0, d1, d2, d3;
            {
                const uint4* hq = reinterpret_cast<const uint4*>(&slot[0][0]);
                d0 = hq[0]; d1 = hq[1]; d2 = hq[2]; d3 = hq[3];
            }
            #pragma unroll
            for (int u = 0; u < KPIPE; ++u) {
                h2 h0q[16];
                h0q[ 0]=u2h2(d0.x); h0q[ 1]=u2h2(d0.y); h0q[ 2]=u2h2(d0.z); h0q[ 3]=u2h2(d0.w);
                h0q[ 4]=u2h2(d1.x); h0q[ 5]=u2h2(d1.y); h0q[ 6]=u2h2(d1.z); h0q[ 7]=u2h2(d1.w);
                h0q[ 8]=u2h2(d2.x); h0q[ 9]=u2h2(d2.y); h0q[10]=u2h2(d2.z); h0q[11]=u2h2(d2.w);
                h0q[12]=u2h2(d3.x); h0q[13]=u2h2(d3.y); h0q[14]=u2h2(d3.z); h0q[15]=u2h2(d3.w);
                if (u + 1 < KPIPE) {
                    const uint4* hq = reinterpret_cast<const uint4*>(&slot[u + 1][0]);
                    d0 = hq[0]; d1 = hq[1]; d2 = hq[2]; d3 = hq[3];
                }

                // CHAIN-SPLIT: wi1 dots (q accums) cover the h1p read-back;
                // wh1 dots in SEPARATE s accums -> post-RT dep chain 8 not 16.
                float qA0 = b1A, qA1 = 0.f, qB0 = b1B, qB1 = 0.f;
                float sA0 = 0.f, sA1 = 0.f, sB0 = 0.f, sB1 = 0.f;
                #pragma unroll
                for (int k = 0; k < 16; k += 2) {
                    qA0 = fdot2(h0q[k],   u2h2(wi1A[k]),   qA0);
                    qA1 = fdot2(h0q[k+1], u2h2(wi1A[k+1]), qA1);
                    qB0 = fdot2(h0q[k],   u2h2(wi1B[k]),   qB0);
                    qB1 = fdot2(h0q[k+1], u2h2(wi1B[k+1]), qB1);
                }
                #pragma unroll
                for (int k = 0; k < 16; k += 2) {
                    sA0 = fdot2(h1p[k],   u2h2(wh1A[k]),   sA0);
                    sA1 = fdot2(h1p[k+1], u2h2(wh1A[k+1]), sA1);
                    sB0 = fdot2(h1p[k],   u2h2(wh1B[k]),   sB0);
                    sB1 = fdot2(h1p[k+1], u2h2(wh1B[k+1]), sB1);
                }
                const float qA = (qA0 + qA1) + (sA0 + sA1);
                const float qB = (qB0 + qB1) + (sB0 + sB1);

                const float wA = fsig(qA);
                float wB;
                { float e = __builtin_amdgcn_exp2f(sclB * qB);
                  wB = __builtin_fmaf(mulB, __builtin_amdgcn_rcpf(1.0f + e), addB); }
                const float mA = dpp_swap1(wA);
                const float mB = dpp_swap1(wB);
                const float iv1 = p ? mA : wA;
                const float fv1 = p ? wA : mA;
                const float gv1 = p ? mB : wB;
                const float ov1 = p ? wB : mB;
                c1 = __builtin_fmaf(fv1, c1, iv1 * gv1);
                const float h1 = ov1 * ftanh(c1);
                h1last = h1;

                LDS_ORDER();
                h1sm[j] = (unsigned short)__half_as_ushort(__float2half_rn(h1));
                LDS_ORDER();
                {
                    const uint4* hp = reinterpret_cast<const uint4*>(h1sm);
                    uint4 a0 = hp[0], a1 = hp[1], a2 = hp[2], a3 = hp[3];
                    h1p[ 0]=u2h2(a0.x); h1p[ 1]=u2h2(a0.y); h1p[ 2]=u2h2(a0.z); h1p[ 3]=u2h2(a0.w);
                    h1p[ 4]=u2h2(a1.x); h1p[ 5]=u2h2(a1.y); h1p[ 6]=u2h2(a1.z); h1p[ 7]=u2h2(a1.w);
                    h1p[ 8]=u2h2(a2.x); h1p[ 9]=u2h2(a2.y); h1p[10]=u2h2(a2.z); h1p[11]=u2h2(a2.w);
                    h1p[12]=u2h2(a3.x); h1p[13]=u2h2(a3.y); h1p[14]=u2h2(a3.z); h1p[15]=u2h2(a3.w);
                }
            }
        };

        LGKM_FENCE();
        __builtin_amdgcn_s_barrier();     // prologue
        for (int s = 0; s < NSUPER; ++s) {
            if (s > 0) consume8(h0buf[(s - 1) & 1]);
            LGKM_FENCE();
            __builtin_amdgcn_s_barrier();
        }
        consume8(h0buf[(NSUPER - 1) & 1]);

        // FC: pair lanes both hold h1[j]; mask odd lanes, 64-lane reduce
        float pFC = p ? 0.0f : h1last * Wfc[j];
        pFC += __shfl_xor(pFC, 32);
        pFC += __shfl_xor(pFC, 16);
        pFC += __shfl_xor(pFC, 8);
        pFC += __shfl_xor(pFC, 4);
        pFC += __shfl_xor(pFC, 2);
        pFC += __shfl_xor(pFC, 1);
        if (lane == 0) out[b] = pFC + bfc[0];
    } else {
        // ================= WAVE 2 : gx producer (R15-identical) ============
        unsigned int wi0A[32], wi0B[32];
        #pragma unroll
        for (int k4 = 0; k4 < 16; ++k4) {
            float4 v;
            v = reinterpret_cast<const float4*>(Wih0 + rA * 64)[k4];
            wi0A[2*k4+0] = pk16(v.x, v.y);  wi0A[2*k4+1] = pk16(v.z, v.w);
            v = reinterpret_cast<const float4*>(Wih0 + rB * 64)[k4];
            wi0B[2*k4+0] = pk16(v.x, v.y);  wi0B[2*k4+1] = pk16(v.z, v.w);
        }
        #pragma unroll
        for (int k = 0; k < 32; ++k)
            asm volatile("" : "+v"(wi0A[k]), "+v"(wi0B[k]));

        const float b0A = bih0[rA] + bhh0[rA];
        const float b0B = bih0[rB] + bhh0[rB];

        // x staging: lane owns 8 consecutive floats of each 512-float block.
        const float* xrow = x + (size_t)b * S_LEN * 64;
        const int tsub = lane >> 3;
        const int kq   = (lane & 7) * 4;

        auto stage = [&](float4 xr0, float4 xr1) {
            uint4 w;
            w.x = pk16(xr0.x, xr0.y);  w.y = pk16(xr0.z, xr0.w);
            w.z = pk16(xr1.x, xr1.y);  w.w = pk16(xr1.z, xr1.w);
            LDS_ORDER();
            *reinterpret_cast<uint4*>(&xbuf[tsub][kq]) = w;
            LDS_ORDER();
        };
        auto compute_block = [&](unsigned int (*dst)[64]) {
            #pragma unroll
            for (int u = 0; u < KPIPE; ++u) {
                uint4 xv[8];
                #pragma unroll
                for (int q = 0; q < 8; ++q)
                    xv[q] = reinterpret_cast<const uint4*>(&xbuf[u][0])[q];
                float gA0 = b0A, gA1 = 0.f, gB0 = b0B, gB1 = 0.f;
                #pragma unroll
                for (int q = 0; q < 8; ++q) {
                    gA0 = fdot2(u2h2(xv[q].x), u2h2(wi0A[4*q+0]), gA0);
                    gA1 = fdot2(u2h2(xv[q].y), u2h2(wi0A[4*q+1]), gA1);
                    gA0 = fdot2(u2h2(xv[q].z), u2h2(wi0A[4*q+2]), gA0);
                    gA1 = fdot2(u2h2(xv[q].w), u2h2(wi0A[4*q+3]), gA1);
                    gB0 = fdot2(u2h2(xv[q].x), u2h2(wi0B[4*q+0]), gB0);
                    gB1 = fdot2(u2h2(xv[q].y), u2h2(wi0B[4*q+1]), gB1);
                    gB0 = fdot2(u2h2(xv[q].z), u2h2(wi0B[4*q+2]), gB0);
                    gB1 = fdot2(u2h2(xv[q].w), u2h2(wi0B[4*q+3]), gB1);
                }
                LDS_ORDER();
                dst[u][lane] = pk16(gA0 + gA1, gB0 + gB1);
                LDS_ORDER();
            }
        };

        // prologue: block 0 sync -> gxbuf[0]; issue block 1 loads
        float4 xr0 = reinterpret_cast<const float4*>(xrow + lane * 8)[0];
        float4 xr1 = reinterpret_cast<const float4*>(xrow + lane * 8 + 4)[0];
        VM_FENCE();
        stage(xr0, xr1);
        compute_block(gxbuf[0]);
        xr0 = reinterpret_cast<const float4*>(xrow + 512 + lane * 8)[0];
        xr1 = reinterpret_cast<const float4*>(xrow + 512 + lane * 8 + 4)[0];

        LGKM_FENCE();
        __builtin_amdgcn_s_barrier();     // prologue

        for (int s = 0; s < NSUPER; ++s) {
            VM_FENCE();                   // block min(s+1,63) landed
            stage(xr0, xr1);
            compute_block(gxbuf[(s + 1) & 1]);
            const int sn = (s + 2 < NSUPER) ? (s + 2) : (NSUPER - 1);
            xr0 = reinterpret_cast<const float4*>(xrow + sn * 512 + lane * 8)[0];
            xr1 = reinterpret_cast<const float4*>(xrow + sn * 512 + lane * 8 + 4)[0];
            LGKM_FENCE();
            __builtin_amdgcn_s_barrier();
        }
    }
}

extern "C" void kernel_launch(void* const* d_in, const int* in_sizes, int n_in,
                              void* d_out, int out_size, void* d_ws, size_t ws_size,
                              hipStream_t stream) {
    (void)in_sizes; (void)n_in; (void)out_size; (void)d_ws; (void)ws_size;
    const float* x    = (const float*)d_in[0];
    const float* Wih0 = (const float*)d_in[1];
    const float* Whh0 = (const float*)d_in[2];
    const float* bih0 = (const float*)d_in[3];
    const float* bhh0 = (const float*)d_in[4];
    const float* Wih1 = (const float*)d_in[5];
    const float* Whh1 = (const float*)d_in[6];
    const float* bih1 = (const float*)d_in[7];
    const float* bhh1 = (const float*)d_in[8];
    const float* Wfc  = (const float*)d_in[9];
    const float* bfc  = (const float*)d_in[10];
    float* out = (float*)d_out;

    hipLaunchKernelGGL(lstm_scan_kernel, dim3(B_SZ), dim3(192), 0, stream,
                       x, Wih0, Whh0, bih0, bhh0, Wih1, Whh1, bih1, bhh1,
                       Wfc, bfc, out);
}

// Round 18
// 203.542 us; speedup vs baseline: 1.0541x; 1.0063x over previous
//
#include <hip/hip_runtime.h>
#include <hip/hip_fp16.h>

#define B_SZ  512
#define S_LEN 512
#define D_IN  64
#define H_DIM 32
#define KPIPE 8                    // steps per super-step (ring depth)
#define NSUPER (S_LEN / KPIPE)     // 64

typedef _Float16 h2 __attribute__((ext_vector_type(2)));

__device__ __forceinline__ float fsig(float x) {
    float e = __builtin_amdgcn_exp2f(x * -1.44269504088896340736f);
    return __builtin_amdgcn_rcpf(1.0f + e);
}
__device__ __forceinline__ float ftanh(float x) {
    float e = __builtin_amdgcn_exp2f(x * -2.88539008177792681472f);
    return __builtin_fmaf(2.0f, __builtin_amdgcn_rcpf(1.0f + e), -1.0f);
}

#if __has_builtin(__builtin_amdgcn_fdot2)
__device__ __forceinline__ float fdot2(h2 a, h2 b, float c) {
    return __builtin_amdgcn_fdot2(a, b, c, false);   // v_dot2_f32_f16
}
#else
__device__ __forceinline__ float fdot2(h2 a, h2 b, float c) {
    return __builtin_fmaf((float)a[1], (float)b[1],
           __builtin_fmaf((float)a[0], (float)b[0], c));
}
#endif

__device__ __forceinline__ h2 u2h2(unsigned int u) { return __builtin_bit_cast(h2, u); }
__device__ __forceinline__ unsigned int pk16(float x, float y) {
    unsigned int lo = __half_as_ushort(__float2half_rn(x));
    unsigned int hi = __half_as_ushort(__float2half_rn(y));
    return lo | (hi << 16);
}

// Exchange with lane^1 on the VALU: v_mov_b32 dpp quad_perm:[1,0,3,2].
__device__ __forceinline__ float dpp_swap1(float x) {
    return __builtin_bit_cast(float, __builtin_amdgcn_mov_dpp(
        __builtin_bit_cast(int, x), 0xB1, 0xF, 0xF, false));
}

// Compiler-only memory fence (no instruction, doesn't drain vmcnt).
#define LDS_ORDER() asm volatile("" ::: "memory")
// LDS-drain + compiler fence, WITHOUT vmcnt drain.
#define LGKM_FENCE() asm volatile("s_waitcnt lgkmcnt(0)" ::: "memory")
// VMEM-drain (x staging loads), lgkm untouched.
#define VM_FENCE()   asm volatile("s_waitcnt vmcnt(0)" ::: "memory")

// ---------------------------------------------------------------------------
// SINGLE fused kernel, THREE-WAVE specialization (R15 structure VERBATIM;
// R17's chain-split reverted — it cost 4%).
// ONE isolated change vs R15: s_setprio(1) on waves 0/1 (chain-critical);
// wave2 (gx producer, slack-rich) stays prio 0. T5 mechanism: role-split
// waves sharing a SIMD -> scheduler favors the critical chains.
// block = 192 thr = 3 waves = ONE batch row; 512 blocks = 1536 waves (6/CU).
//   wave2 = gx producer: stages x one super-step ahead, computes gx block
//           s+1 into ring gxbuf[(s+1)&1].
//   wave0 = layer 0: act -> h0 ring -> Whh0 dots.
//   wave1 = layer 1 + FC: consumes h0 block s-1.
// 65 s_barriers per wave, lgkmcnt-only drains (vmcnt stays in flight).
// ---------------------------------------------------------------------------
__global__ __launch_bounds__(192, 1) void lstm_scan_kernel(
    const float* __restrict__ x,
    const float* __restrict__ Wih0,
    const float* __restrict__ Whh0,
    const float* __restrict__ bih0,
    const float* __restrict__ bhh0,
    const float* __restrict__ Wih1,
    const float* __restrict__ Whh1,
    const float* __restrict__ bih1,
    const float* __restrict__ bhh1,
    const float* __restrict__ Wfc,
    const float* __restrict__ bfc,
    float* __restrict__ out)
{
    const int tid  = threadIdx.x;
    const int lane = tid & 63;
    const int j    = lane >> 1;
    const int p    = lane & 1;
    const int b    = blockIdx.x;
    const int rA   = p ? (32 + j) : j;    // gateA row: p=0 -> i_j, p=1 -> f_j
    const int rB   = rA + 64;             // gateB row: p=0 -> g_j, p=1 -> o_j

    __shared__ unsigned short h0buf[2][KPIPE][32];   // wave0 -> wave1
    __shared__ unsigned short h1sm[32];              // wave1-private
    __shared__ unsigned int   xbuf[KPIPE][32];       // wave2-private (x fp16x2)
    __shared__ unsigned int   gxbuf[2][KPIPE][64];   // wave2 -> wave0

    // gateA (i or f): sigmoid. gateB: p=0 -> tanh (g), p=1 -> sigmoid (o).
    const float sclB = p ? -1.44269504088896340736f : -2.88539008177792681472f;
    const float mulB = p ?  1.0f : 2.0f;
    const float addB = p ?  0.0f : -1.0f;

    if (tid < 64) {
        // ================= WAVE 0 : layer 0 (R15-identical) ================
        __builtin_amdgcn_s_setprio(1);
        unsigned int wh0A[16], wh0B[16];
        #pragma unroll
        for (int k4 = 0; k4 < 8; ++k4) {
            float4 v;
            v = reinterpret_cast<const float4*>(Whh0 + rA * 32)[k4];
            wh0A[2*k4+0] = pk16(v.x, v.y);  wh0A[2*k4+1] = pk16(v.z, v.w);
            v = reinterpret_cast<const float4*>(Whh0 + rB * 32)[k4];
            wh0B[2*k4+0] = pk16(v.x, v.y);  wh0B[2*k4+1] = pk16(v.z, v.w);
        }
        #pragma unroll
        for (int k = 0; k < 16; ++k)
            asm volatile("" : "+v"(wh0A[k]), "+v"(wh0B[k]));

        h2 h0p[16];
        #pragma unroll
        for (int k = 0; k < 16; ++k) h0p[k] = (h2){0, 0};
        float c0 = 0.f;
        float zA = 0.f, zB = 0.f;         // Whh0.h0(t-1); 0 at t=0

        LGKM_FENCE();
        __builtin_amdgcn_s_barrier();     // prologue: gx block 0 ready

        for (int s = 0; s < NSUPER; ++s) {
            // fetch this super-step's 8 gx values (block fully written in s-1)
            unsigned int gxr[KPIPE];
            LDS_ORDER();
            #pragma unroll
            for (int u = 0; u < KPIPE; ++u) gxr[u] = gxbuf[s & 1][u][lane];
            LDS_ORDER();

            unsigned short (*slot)[32] = h0buf[s & 1];
            #pragma unroll
            for (int u = 0; u < KPIPE; ++u) {
                h2 g = u2h2(gxr[u]);
                const float aA = zA + (float)g[0];
                const float aB = zB + (float)g[1];

                // act chain + DPP combine + cell + h0(t)
                const float vA = fsig(aA);
                float vB;
                { float e = __builtin_amdgcn_exp2f(sclB * aB);
                  vB = __builtin_fmaf(mulB, __builtin_amdgcn_rcpf(1.0f + e), addB); }
                const float nA = dpp_swap1(vA);
                const float nB = dpp_swap1(vB);
                const float iv = p ? nA : vA;
                const float fv = p ? vA : nA;
                const float gv = p ? nB : vB;
                const float ov = p ? vB : nB;
                c0 = __builtin_fmaf(fv, c0, iv * gv);
                const float h0 = ov * ftanh(c0);

                // publish h0(t); read back own packed copy
                LDS_ORDER();
                slot[u][j] = (unsigned short)__half_as_ushort(__float2half_rn(h0));
                LDS_ORDER();
                {
                    const uint4* hp = reinterpret_cast<const uint4*>(&slot[u][0]);
                    uint4 a0 = hp[0], a1 = hp[1], a2 = hp[2], a3 = hp[3];
                    h0p[ 0]=u2h2(a0.x); h0p[ 1]=u2h2(a0.y); h0p[ 2]=u2h2(a0.z); h0p[ 3]=u2h2(a0.w);
                    h0p[ 4]=u2h2(a1.x); h0p[ 5]=u2h2(a1.y); h0p[ 6]=u2h2(a1.z); h0p[ 7]=u2h2(a1.w);
                    h0p[ 8]=u2h2(a2.x); h0p[ 9]=u2h2(a2.y); h0p[10]=u2h2(a2.z); h0p[11]=u2h2(a2.w);
                    h0p[12]=u2h2(a3.x); h0p[13]=u2h2(a3.y); h0p[14]=u2h2(a3.z); h0p[15]=u2h2(a3.w);
                }

                // Whh0 . h0(t) -> carried into step t+1
                float zA0 = 0.f, zA1 = 0.f, zB0 = 0.f, zB1 = 0.f;
                #pragma unroll
                for (int k = 0; k < 16; k += 2) {
                    zA0 = fdot2(h0p[k],   u2h2(wh0A[k]),   zA0);
                    zA1 = fdot2(h0p[k+1], u2h2(wh0A[k+1]), zA1);
                    zB0 = fdot2(h0p[k],   u2h2(wh0B[k]),   zB0);
                    zB1 = fdot2(h0p[k+1], u2h2(wh0B[k+1]), zB1);
                }
                zA = zA0 + zA1;  zB = zB0 + zB1;
            }
            LGKM_FENCE();
            __builtin_amdgcn_s_barrier();
        }
    } else if (tid < 128) {
        // ============ WAVE 1 : layer 1 + FC (R15-identical) ================
        __builtin_amdgcn_s_setprio(1);
        unsigned int wi1A[16], wi1B[16], wh1A[16], wh1B[16];
        #pragma unroll
        for (int k4 = 0; k4 < 8; ++k4) {
            float4 v;
            v = reinterpret_cast<const float4*>(Wih1 + rA * 32)[k4];
            wi1A[2*k4+0] = pk16(v.x, v.y);  wi1A[2*k4+1] = pk16(v.z, v.w);
            v = reinterpret_cast<const float4*>(Wih1 + rB * 32)[k4];
            wi1B[2*k4+0] = pk16(v.x, v.y);  wi1B[2*k4+1] = pk16(v.z, v.w);
            v = reinterpret_cast<const float4*>(Whh1 + rA * 32)[k4];
            wh1A[2*k4+0] = pk16(v.x, v.y);  wh1A[2*k4+1] = pk16(v.z, v.w);
            v = reinterpret_cast<const float4*>(Whh1 + rB * 32)[k4];
            wh1B[2*k4+0] = pk16(v.x, v.y);  wh1B[2*k4+1] = pk16(v.z, v.w);
        }
        #pragma unroll
        for (int k = 0; k < 16; ++k)
            asm volatile("" : "+v"(wi1A[k]), "+v"(wi1B[k]),
                              "+v"(wh1A[k]), "+v"(wh1B[k]));

        const float b1A = bih1[rA] + bhh1[rA];
        const float b1B = bih1[rB] + bhh1[rB];

        h2 h1p[16];
        #pragma unroll
        for (int k = 0; k < 16; ++k) h1p[k] = (h2){0, 0};   // h1(-1) = 0
        float c1 = 0.f;
        float h1last = 0.f;

        auto consume8 = [&](const unsigned short (*slot)[32]) {
            uint4 d0, d1, d2, d3;
            {
                const uint4* hq = reinterpret_cast<const uint4*>(&slot[0][0]);
                d0 = hq[0]; d1 = hq[1]; d2 = hq[2]; d3 = hq[3];
            }
            #pragma unroll
            for (int u = 0; u < KPIPE; ++u) {
                h2 h0q[16];
                h0q[ 0]=u2h2(d0.x); h0q[ 1]=u2h2(d0.y); h0q[ 2]=u2h2(d0.z); h0q[ 3]=u2h2(d0.w);
                h0q[ 4]=u2h2(d1.x); h0q[ 5]=u2h2(d1.y); h0q[ 6]=u2h2(d1.z); h0q[ 7]=u2h2(d1.w);
                h0q[ 8]=u2h2(d2.x); h0q[ 9]=u2h2(d2.y); h0q[10]=u2h2(d2.z); h0q[11]=u2h2(d2.w);
                h0q[12]=u2h2(d3.x); h0q[13]=u2h2(d3.y); h0q[14]=u2h2(d3.z); h0q[15]=u2h2(d3.w);
                if (u + 1 < KPIPE) {
                    const uint4* hq = reinterpret_cast<const uint4*>(&slot[u + 1][0]);
                    d0 = hq[0]; d1 = hq[1]; d2 = hq[2]; d3 = hq[3];
                }

                // wi1 dots cover the h1p RT; wh1 dots continue same accums
                // (R15 order — R17's split accums regressed, reverted).
                float qA0 = b1A, qA1 = 0.f, qB0 = b1B, qB1 = 0.f;
                #pragma unroll
                for (int k = 0; k < 16; k += 2) {
                    qA0 = fdot2(h0q[k],   u2h2(wi1A[k]),   qA0);
                    qA1 = fdot2(h0q[k+1], u2h2(wi1A[k+1]), qA1);
                    qB0 = fdot2(h0q[k],   u2h2(wi1B[k]),   qB0);
                    qB1 = fdot2(h0q[k+1], u2h2(wi1B[k+1]), qB1);
                }
                #pragma unroll
                for (int k = 0; k < 16; k += 2) {
                    qA0 = fdot2(h1p[k],   u2h2(wh1A[k]),   qA0);
                    qA1 = fdot2(h1p[k+1], u2h2(wh1A[k+1]), qA1);
                    qB0 = fdot2(h1p[k],   u2h2(wh1B[k]),   qB0);
                    qB1 = fdot2(h1p[k+1], u2h2(wh1B[k+1]), qB1);
                }
                const float qA = qA0 + qA1;
                const float qB = qB0 + qB1;

                const float wA = fsig(qA);
                float wB;
                { float e = __builtin_amdgcn_exp2f(sclB * qB);
                  wB = __builtin_fmaf(mulB, __builtin_amdgcn_rcpf(1.0f + e), addB); }
                const float mA = dpp_swap1(wA);
                const float mB = dpp_swap1(wB);
                const float iv1 = p ? mA : wA;
                const float fv1 = p ? wA : mA;
                const float gv1 = p ? mB : wB;
                const float ov1 = p ? wB : mB;
                c1 = __builtin_fmaf(fv1, c1, iv1 * gv1);
                const float h1 = ov1 * ftanh(c1);
                h1last = h1;

                LDS_ORDER();
                h1sm[j] = (unsigned short)__half_as_ushort(__float2half_rn(h1));
                LDS_ORDER();
                {
                    const uint4* hp = reinterpret_cast<const uint4*>(h1sm);
                    uint4 a0 = hp[0], a1 = hp[1], a2 = hp[2], a3 = hp[3];
                    h1p[ 0]=u2h2(a0.x); h1p[ 1]=u2h2(a0.y); h1p[ 2]=u2h2(a0.z); h1p[ 3]=u2h2(a0.w);
                    h1p[ 4]=u2h2(a1.x); h1p[ 5]=u2h2(a1.y); h1p[ 6]=u2h2(a1.z); h1p[ 7]=u2h2(a1.w);
                    h1p[ 8]=u2h2(a2.x); h1p[ 9]=u2h2(a2.y); h1p[10]=u2h2(a2.z); h1p[11]=u2h2(a2.w);
                    h1p[12]=u2h2(a3.x); h1p[13]=u2h2(a3.y); h1p[14]=u2h2(a3.z); h1p[15]=u2h2(a3.w);
                }
            }
        };

        LGKM_FENCE();
        __builtin_amdgcn_s_barrier();     // prologue
        for (int s = 0; s < NSUPER; ++s) {
            if (s > 0) consume8(h0buf[(s - 1) & 1]);
            LGKM_FENCE();
            __builtin_amdgcn_s_barrier();
        }
        consume8(h0buf[(NSUPER - 1) & 1]);

        // FC: pair lanes both hold h1[j]; mask odd lanes, 64-lane reduce
        float pFC = p ? 0.0f : h1last * Wfc[j];
        pFC += __shfl_xor(pFC, 32);
        pFC += __shfl_xor(pFC, 16);
        pFC += __shfl_xor(pFC, 8);
        pFC += __shfl_xor(pFC, 4);
        pFC += __shfl_xor(pFC, 2);
        pFC += __shfl_xor(pFC, 1);
        if (lane == 0) out[b] = pFC + bfc[0];
    } else {
        // ================= WAVE 2 : gx producer (R15-identical, prio 0) ====
        unsigned int wi0A[32], wi0B[32];
        #pragma unroll
        for (int k4 = 0; k4 < 16; ++k4) {
            float4 v;
            v = reinterpret_cast<const float4*>(Wih0 + rA * 64)[k4];
            wi0A[2*k4+0] = pk16(v.x, v.y);  wi0A[2*k4+1] = pk16(v.z, v.w);
            v = reinterpret_cast<const float4*>(Wih0 + rB * 64)[k4];
            wi0B[2*k4+0] = pk16(v.x, v.y);  wi0B[2*k4+1] = pk16(v.z, v.w);
        }
        #pragma unroll
        for (int k = 0; k < 32; ++k)
            asm volatile("" : "+v"(wi0A[k]), "+v"(wi0B[k]));

        const float b0A = bih0[rA] + bhh0[rA];
        const float b0B = bih0[rB] + bhh0[rB];

        // x staging: lane owns 8 consecutive floats of each 512-float block.
        const float* xrow = x + (size_t)b * S_LEN * 64;
        const int tsub = lane >> 3;
        const int kq   = (lane & 7) * 4;

        auto stage = [&](float4 xr0, float4 xr1) {
            uint4 w;
            w.x = pk16(xr0.x, xr0.y);  w.y = pk16(xr0.z, xr0.w);
            w.z = pk16(xr1.x, xr1.y);  w.w = pk16(xr1.z, xr1.w);
            LDS_ORDER();
            *reinterpret_cast<uint4*>(&xbuf[tsub][kq]) = w;
            LDS_ORDER();
        };
        auto compute_block = [&](unsigned int (*dst)[64]) {
            #pragma unroll
            for (int u = 0; u < KPIPE; ++u) {
                uint4 xv[8];
                #pragma unroll
                for (int q = 0; q < 8; ++q)
                    xv[q] = reinterpret_cast<const uint4*>(&xbuf[u][0])[q];
                float gA0 = b0A, gA1 = 0.f, gB0 = b0B, gB1 = 0.f;
                #pragma unroll
                for (int q = 0; q < 8; ++q) {
                    gA0 = fdot2(u2h2(xv[q].x), u2h2(wi0A[4*q+0]), gA0);
                    gA1 = fdot2(u2h2(xv[q].y), u2h2(wi0A[4*q+1]), gA1);
                    gA0 = fdot2(u2h2(xv[q].z), u2h2(wi0A[4*q+2]), gA0);
                    gA1 = fdot2(u2h2(xv[q].w), u2h2(wi0A[4*q+3]), gA1);
                    gB0 = fdot2(u2h2(xv[q].x), u2h2(wi0B[4*q+0]), gB0);
                    gB1 = fdot2(u2h2(xv[q].y), u2h2(wi0B[4*q+1]), gB1);
                    gB0 = fdot2(u2h2(xv[q].z), u2h2(wi0B[4*q+2]), gB0);
                    gB1 = fdot2(u2h2(xv[q].w), u2h2(wi0B[4*q+3]), gB1);
                }
                LDS_ORDER();
                dst[u][lane] = pk16(gA0 + gA1, gB0 + gB1);
                LDS_ORDER();
            }
        };

        // prologue: block 0 sync -> gxbuf[0]; issue block 1 loads
        float4 xr0 = reinterpret_cast<const float4*>(xrow + lane * 8)[0];
        float4 xr1 = reinterpret_cast<const float4*>(xrow + lane * 8 + 4)[0];
        VM_FENCE();
        stage(xr0, xr1);
        compute_block(gxbuf[0]);
        xr0 = reinterpret_cast<const float4*>(xrow + 512 + lane * 8)[0];
        xr1 = reinterpret_cast<const float4*>(xrow + 512 + lane * 8 + 4)[0];

        LGKM_FENCE();
        __builtin_amdgcn_s_barrier();     // prologue

        for (int s = 0; s < NSUPER; ++s) {
            VM_FENCE();                   // block min(s+1,63) landed
            stage(xr0, xr1);
            compute_block(gxbuf[(s + 1) & 1]);
            const int sn = (s + 2 < NSUPER) ? (s + 2) : (NSUPER - 1);
            xr0 = reinterpret_cast<const float4*>(xrow + sn * 512 + lane * 8)[0];
            xr1 = reinterpret_cast<const float4*>(xrow + sn * 512 + lane * 8 + 4)[0];
            LGKM_FENCE();
            __builtin_amdgcn_s_barrier();
        }
    }
}

extern "C" void kernel_launch(void* const* d_in, const int* in_sizes, int n_in,
                              void* d_out, int out_size, void* d_ws, size_t ws_size,
                              hipStream_t stream) {
    (void)in_sizes; (void)n_in; (void)out_size; (void)d_ws; (void)ws_size;
    const float* x    = (const float*)d_in[0];
    const float* Wih0 = (const float*)d_in[1];
    const float* Whh0 = (const float*)d_in[2];
    const float* bih0 = (const float*)d_in[3];
    const float* bhh0 = (const float*)d_in[4];
    const float* Wih1 = (const float*)d_in[5];
    const float* Whh1 = (const float*)d_in[6];
    const float* bih1 = (const float*)d_in[7];
    const float* bhh1 = (const float*)d_in[8];
    const float* Wfc  = (const float*)d_in[9];
    const float* bfc  = (const float*)d_in[10];
    float* out = (float*)d_out;

    hipLaunchKernelGGL(lstm_scan_kernel, dim3(B_SZ), dim3(192), 0, stream,
                       x, Wih0, Whh0, bih0, bhh0, Wih1, Whh1, bih1, bhh1,
                       Wfc, bfc, out);
}

// Round 19
// 197.964 us; speedup vs baseline: 1.0838x; 1.0282x over previous
//
#include <hip/hip_runtime.h>
#include <hip/hip_fp16.h>

#define B_SZ  512
#define S_LEN 512
#define D_IN  64
#define H_DIM 32
#define KPIPE 8                    // steps per super-step (ring depth)
#define NSUPER (S_LEN / KPIPE)     // 64

typedef _Float16 h2 __attribute__((ext_vector_type(2)));

__device__ __forceinline__ float fsig(float x) {
    float e = __builtin_amdgcn_exp2f(x * -1.44269504088896340736f);
    return __builtin_amdgcn_rcpf(1.0f + e);
}
__device__ __forceinline__ float ftanh(float x) {
    float e = __builtin_amdgcn_exp2f(x * -2.88539008177792681472f);
    return __builtin_fmaf(2.0f, __builtin_amdgcn_rcpf(1.0f + e), -1.0f);
}

#if __has_builtin(__builtin_amdgcn_fdot2)
__device__ __forceinline__ float fdot2(h2 a, h2 b, float c) {
    return __builtin_amdgcn_fdot2(a, b, c, false);   // v_dot2_f32_f16
}
#else
__device__ __forceinline__ float fdot2(h2 a, h2 b, float c) {
    return __builtin_fmaf((float)a[1], (float)b[1],
           __builtin_fmaf((float)a[0], (float)b[0], c));
}
#endif

__device__ __forceinline__ h2 u2h2(unsigned int u) { return __builtin_bit_cast(h2, u); }
__device__ __forceinline__ unsigned int pk16(float x, float y) {
    unsigned int lo = __half_as_ushort(__float2half_rn(x));
    unsigned int hi = __half_as_ushort(__float2half_rn(y));
    return lo | (hi << 16);
}

// Exchange with lane^1 on the VALU: v_mov_b32 dpp quad_perm:[1,0,3,2].
__device__ __forceinline__ float dpp_swap1(float x) {
    return __builtin_bit_cast(float, __builtin_amdgcn_mov_dpp(
        __builtin_bit_cast(int, x), 0xB1, 0xF, 0xF, false));
}

// Compiler-only memory fence (no instruction, doesn't drain vmcnt).
#define LDS_ORDER() asm volatile("" ::: "memory")
// LDS-drain + compiler fence, WITHOUT vmcnt drain.
#define LGKM_FENCE() asm volatile("s_waitcnt lgkmcnt(0)" ::: "memory")
// VMEM-drain (x staging loads), lgkm untouched.
#define VM_FENCE()   asm volatile("s_waitcnt vmcnt(0)" ::: "memory")

// ---------------------------------------------------------------------------
// FINAL: SINGLE fused kernel, THREE-WAVE specialization (R15, the best
// measured configuration: 197 µs). R16/R17/R18 levers (KPIPE=16, chain
// split, setprio) all regressed or were null — reverted.
// block = 192 thr = 3 waves = ONE batch row; 512 blocks = 1536 waves (6/CU).
//   wave2 = gx producer: stages x one super-step ahead, computes gx block
//           s+1 into ring gxbuf[(s+1)&1].
//   wave0 = layer 0: act -> h0 ring -> Whh0 dots.
//   wave1 = layer 1 + FC: consumes h0 block s-1.
// 65 s_barriers per wave, lgkmcnt-only drains (vmcnt stays in flight).
// Structural plateau: 512 serial steps x 3-wave split = 1536 waves max on
// 1024 SIMDs; instruction stream ~ math floor; ~57% issue packing measured.
// ---------------------------------------------------------------------------
__global__ __launch_bounds__(192, 1) void lstm_scan_kernel(
    const float* __restrict__ x,
    const float* __restrict__ Wih0,
    const float* __restrict__ Whh0,
    const float* __restrict__ bih0,
    const float* __restrict__ bhh0,
    const float* __restrict__ Wih1,
    const float* __restrict__ Whh1,
    const float* __restrict__ bih1,
    const float* __restrict__ bhh1,
    const float* __restrict__ Wfc,
    const float* __restrict__ bfc,
    float* __restrict__ out)
{
    const int tid  = threadIdx.x;
    const int lane = tid & 63;
    const int j    = lane >> 1;
    const int p    = lane & 1;
    const int b    = blockIdx.x;
    const int rA   = p ? (32 + j) : j;    // gateA row: p=0 -> i_j, p=1 -> f_j
    const int rB   = rA + 64;             // gateB row: p=0 -> g_j, p=1 -> o_j

    __shared__ unsigned short h0buf[2][KPIPE][32];   // wave0 -> wave1
    __shared__ unsigned short h1sm[32];              // wave1-private
    __shared__ unsigned int   xbuf[KPIPE][32];       // wave2-private (x fp16x2)
    __shared__ unsigned int   gxbuf[2][KPIPE][64];   // wave2 -> wave0

    // gateA (i or f): sigmoid. gateB: p=0 -> tanh (g), p=1 -> sigmoid (o).
    const float sclB = p ? -1.44269504088896340736f : -2.88539008177792681472f;
    const float mulB = p ?  1.0f : 2.0f;
    const float addB = p ?  0.0f : -1.0f;

    if (tid < 64) {
        // ================= WAVE 0 : layer 0 ================
        unsigned int wh0A[16], wh0B[16];
        #pragma unroll
        for (int k4 = 0; k4 < 8; ++k4) {
            float4 v;
            v = reinterpret_cast<const float4*>(Whh0 + rA * 32)[k4];
            wh0A[2*k4+0] = pk16(v.x, v.y);  wh0A[2*k4+1] = pk16(v.z, v.w);
            v = reinterpret_cast<const float4*>(Whh0 + rB * 32)[k4];
            wh0B[2*k4+0] = pk16(v.x, v.y);  wh0B[2*k4+1] = pk16(v.z, v.w);
        }
        #pragma unroll
        for (int k = 0; k < 16; ++k)
            asm volatile("" : "+v"(wh0A[k]), "+v"(wh0B[k]));

        h2 h0p[16];
        #pragma unroll
        for (int k = 0; k < 16; ++k) h0p[k] = (h2){0, 0};
        float c0 = 0.f;
        float zA = 0.f, zB = 0.f;         // Whh0.h0(t-1); 0 at t=0

        LGKM_FENCE();
        __builtin_amdgcn_s_barrier();     // prologue: gx block 0 ready

        for (int s = 0; s < NSUPER; ++s) {
            // fetch this super-step's 8 gx values (block fully written in s-1)
            unsigned int gxr[KPIPE];
            LDS_ORDER();
            #pragma unroll
            for (int u = 0; u < KPIPE; ++u) gxr[u] = gxbuf[s & 1][u][lane];
            LDS_ORDER();

            unsigned short (*slot)[32] = h0buf[s & 1];
            #pragma unroll
            for (int u = 0; u < KPIPE; ++u) {
                h2 g = u2h2(gxr[u]);
                const float aA = zA + (float)g[0];
                const float aB = zB + (float)g[1];

                // act chain + DPP combine + cell + h0(t)
                const float vA = fsig(aA);
                float vB;
                { float e = __builtin_amdgcn_exp2f(sclB * aB);
                  vB = __builtin_fmaf(mulB, __builtin_amdgcn_rcpf(1.0f + e), addB); }
                const float nA = dpp_swap1(vA);
                const float nB = dpp_swap1(vB);
                const float iv = p ? nA : vA;
                const float fv = p ? vA : nA;
                const float gv = p ? nB : vB;
                const float ov = p ? vB : nB;
                c0 = __builtin_fmaf(fv, c0, iv * gv);
                const float h0 = ov * ftanh(c0);

                // publish h0(t); read back own packed copy
                LDS_ORDER();
                slot[u][j] = (unsigned short)__half_as_ushort(__float2half_rn(h0));
                LDS_ORDER();
                {
                    const uint4* hp = reinterpret_cast<const uint4*>(&slot[u][0]);
                    uint4 a0 = hp[0], a1 = hp[1], a2 = hp[2], a3 = hp[3];
                    h0p[ 0]=u2h2(a0.x); h0p[ 1]=u2h2(a0.y); h0p[ 2]=u2h2(a0.z); h0p[ 3]=u2h2(a0.w);
                    h0p[ 4]=u2h2(a1.x); h0p[ 5]=u2h2(a1.y); h0p[ 6]=u2h2(a1.z); h0p[ 7]=u2h2(a1.w);
                    h0p[ 8]=u2h2(a2.x); h0p[ 9]=u2h2(a2.y); h0p[10]=u2h2(a2.z); h0p[11]=u2h2(a2.w);
                    h0p[12]=u2h2(a3.x); h0p[13]=u2h2(a3.y); h0p[14]=u2h2(a3.z); h0p[15]=u2h2(a3.w);
                }

                // Whh0 . h0(t) -> carried into step t+1
                float zA0 = 0.f, zA1 = 0.f, zB0 = 0.f, zB1 = 0.f;
                #pragma unroll
                for (int k = 0; k < 16; k += 2) {
                    zA0 = fdot2(h0p[k],   u2h2(wh0A[k]),   zA0);
                    zA1 = fdot2(h0p[k+1], u2h2(wh0A[k+1]), zA1);
                    zB0 = fdot2(h0p[k],   u2h2(wh0B[k]),   zB0);
                    zB1 = fdot2(h0p[k+1], u2h2(wh0B[k+1]), zB1);
                }
                zA = zA0 + zA1;  zB = zB0 + zB1;
            }
            LGKM_FENCE();
            __builtin_amdgcn_s_barrier();
        }
    } else if (tid < 128) {
        // ============ WAVE 1 : layer 1 + FC ================
        unsigned int wi1A[16], wi1B[16], wh1A[16], wh1B[16];
        #pragma unroll
        for (int k4 = 0; k4 < 8; ++k4) {
            float4 v;
            v = reinterpret_cast<const float4*>(Wih1 + rA * 32)[k4];
            wi1A[2*k4+0] = pk16(v.x, v.y);  wi1A[2*k4+1] = pk16(v.z, v.w);
            v = reinterpret_cast<const float4*>(Wih1 + rB * 32)[k4];
            wi1B[2*k4+0] = pk16(v.x, v.y);  wi1B[2*k4+1] = pk16(v.z, v.w);
            v = reinterpret_cast<const float4*>(Whh1 + rA * 32)[k4];
            wh1A[2*k4+0] = pk16(v.x, v.y);  wh1A[2*k4+1] = pk16(v.z, v.w);
            v = reinterpret_cast<const float4*>(Whh1 + rB * 32)[k4];
            wh1B[2*k4+0] = pk16(v.x, v.y);  wh1B[2*k4+1] = pk16(v.z, v.w);
        }
        #pragma unroll
        for (int k = 0; k < 16; ++k)
            asm volatile("" : "+v"(wi1A[k]), "+v"(wi1B[k]),
                              "+v"(wh1A[k]), "+v"(wh1B[k]));

        const float b1A = bih1[rA] + bhh1[rA];
        const float b1B = bih1[rB] + bhh1[rB];

        h2 h1p[16];
        #pragma unroll
        for (int k = 0; k < 16; ++k) h1p[k] = (h2){0, 0};   // h1(-1) = 0
        float c1 = 0.f;
        float h1last = 0.f;

        auto consume8 = [&](const unsigned short (*slot)[32]) {
            uint4 d0, d1, d2, d3;
            {
                const uint4* hq = reinterpret_cast<const uint4*>(&slot[0][0]);
                d0 = hq[0]; d1 = hq[1]; d2 = hq[2]; d3 = hq[3];
            }
            #pragma unroll
            for (int u = 0; u < KPIPE; ++u) {
                h2 h0q[16];
                h0q[ 0]=u2h2(d0.x); h0q[ 1]=u2h2(d0.y); h0q[ 2]=u2h2(d0.z); h0q[ 3]=u2h2(d0.w);
                h0q[ 4]=u2h2(d1.x); h0q[ 5]=u2h2(d1.y); h0q[ 6]=u2h2(d1.z); h0q[ 7]=u2h2(d1.w);
                h0q[ 8]=u2h2(d2.x); h0q[ 9]=u2h2(d2.y); h0q[10]=u2h2(d2.z); h0q[11]=u2h2(d2.w);
                h0q[12]=u2h2(d3.x); h0q[13]=u2h2(d3.y); h0q[14]=u2h2(d3.z); h0q[15]=u2h2(d3.w);
                if (u + 1 < KPIPE) {
                    const uint4* hq = reinterpret_cast<const uint4*>(&slot[u + 1][0]);
                    d0 = hq[0]; d1 = hq[1]; d2 = hq[2]; d3 = hq[3];
                }

                // wi1 dots cover the h1p read-back; wh1 dots continue same
                // accumulators (R15 order).
                float qA0 = b1A, qA1 = 0.f, qB0 = b1B, qB1 = 0.f;
                #pragma unroll
                for (int k = 0; k < 16; k += 2) {
                    qA0 = fdot2(h0q[k],   u2h2(wi1A[k]),   qA0);
                    qA1 = fdot2(h0q[k+1], u2h2(wi1A[k+1]), qA1);
                    qB0 = fdot2(h0q[k],   u2h2(wi1B[k]),   qB0);
                    qB1 = fdot2(h0q[k+1], u2h2(wi1B[k+1]), qB1);
                }
                #pragma unroll
                for (int k = 0; k < 16; k += 2) {
                    qA0 = fdot2(h1p[k],   u2h2(wh1A[k]),   qA0);
                    qA1 = fdot2(h1p[k+1], u2h2(wh1A[k+1]), qA1);
                    qB0 = fdot2(h1p[k],   u2h2(wh1B[k]),   qB0);
                    qB1 = fdot2(h1p[k+1], u2h2(wh1B[k+1]), qB1);
                }
                const float qA = qA0 + qA1;
                const float qB = qB0 + qB1;

                const float wA = fsig(qA);
                float wB;
                { float e = __builtin_amdgcn_exp2f(sclB * qB);
                  wB = __builtin_fmaf(mulB, __builtin_amdgcn_rcpf(1.0f + e), addB); }
                const float mA = dpp_swap1(wA);
                const float mB = dpp_swap1(wB);
                const float iv1 = p ? mA : wA;
                const float fv1 = p ? wA : mA;
                const float gv1 = p ? mB : wB;
                const float ov1 = p ? wB : mB;
                c1 = __builtin_fmaf(fv1, c1, iv1 * gv1);
                const float h1 = ov1 * ftanh(c1);
                h1last = h1;

                LDS_ORDER();
                h1sm[j] = (unsigned short)__half_as_ushort(__float2half_rn(h1));
                LDS_ORDER();
                {
                    const uint4* hp = reinterpret_cast<const uint4*>(h1sm);
                    uint4 a0 = hp[0], a1 = hp[1], a2 = hp[2], a3 = hp[3];
                    h1p[ 0]=u2h2(a0.x); h1p[ 1]=u2h2(a0.y); h1p[ 2]=u2h2(a0.z); h1p[ 3]=u2h2(a0.w);
                    h1p[ 4]=u2h2(a1.x); h1p[ 5]=u2h2(a1.y); h1p[ 6]=u2h2(a1.z); h1p[ 7]=u2h2(a1.w);
                    h1p[ 8]=u2h2(a2.x); h1p[ 9]=u2h2(a2.y); h1p[10]=u2h2(a2.z); h1p[11]=u2h2(a2.w);
                    h1p[12]=u2h2(a3.x); h1p[13]=u2h2(a3.y); h1p[14]=u2h2(a3.z); h1p[15]=u2h2(a3.w);
                }
            }
        };

        LGKM_FENCE();
        __builtin_amdgcn_s_barrier();     // prologue
        for (int s = 0; s < NSUPER; ++s) {
            if (s > 0) consume8(h0buf[(s - 1) & 1]);
            LGKM_FENCE();
            __builtin_amdgcn_s_barrier();
        }
        consume8(h0buf[(NSUPER - 1) & 1]);

        // FC: pair lanes both hold h1[j]; mask odd lanes, 64-lane reduce
        float pFC = p ? 0.0f : h1last * Wfc[j];
        pFC += __shfl_xor(pFC, 32);
        pFC += __shfl_xor(pFC, 16);
        pFC += __shfl_xor(pFC, 8);
        pFC += __shfl_xor(pFC, 4);
        pFC += __shfl_xor(pFC, 2);
        pFC += __shfl_xor(pFC, 1);
        if (lane == 0) out[b] = pFC + bfc[0];
    } else {
        // ================= WAVE 2 : gx producer ============================
        unsigned int wi0A[32], wi0B[32];
        #pragma unroll
        for (int k4 = 0; k4 < 16; ++k4) {
            float4 v;
            v = reinterpret_cast<const float4*>(Wih0 + rA * 64)[k4];
            wi0A[2*k4+0] = pk16(v.x, v.y);  wi0A[2*k4+1] = pk16(v.z, v.w);
            v = reinterpret_cast<const float4*>(Wih0 + rB * 64)[k4];
            wi0B[2*k4+0] = pk16(v.x, v.y);  wi0B[2*k4+1] = pk16(v.z, v.w);
        }
        #pragma unroll
        for (int k = 0; k < 32; ++k)
            asm volatile("" : "+v"(wi0A[k]), "+v"(wi0B[k]));

        const float b0A = bih0[rA] + bhh0[rA];
        const float b0B = bih0[rB] + bhh0[rB];

        // x staging: lane owns 8 consecutive floats of each 512-float block.
        const float* xrow = x + (size_t)b * S_LEN * 64;
        const int tsub = lane >> 3;
        const int kq   = (lane & 7) * 4;

        auto stage = [&](float4 xr0, float4 xr1) {
            uint4 w;
            w.x = pk16(xr0.x, xr0.y);  w.y = pk16(xr0.z, xr0.w);
            w.z = pk16(xr1.x, xr1.y);  w.w = pk16(xr1.z, xr1.w);
            LDS_ORDER();
            *reinterpret_cast<uint4*>(&xbuf[tsub][kq]) = w;
            LDS_ORDER();
        };
        auto compute_block = [&](unsigned int (*dst)[64]) {
            #pragma unroll
            for (int u = 0; u < KPIPE; ++u) {
                uint4 xv[8];
                #pragma unroll
                for (int q = 0; q < 8; ++q)
                    xv[q] = reinterpret_cast<const uint4*>(&xbuf[u][0])[q];
                float gA0 = b0A, gA1 = 0.f, gB0 = b0B, gB1 = 0.f;
                #pragma unroll
                for (int q = 0; q < 8; ++q) {
                    gA0 = fdot2(u2h2(xv[q].x), u2h2(wi0A[4*q+0]), gA0);
                    gA1 = fdot2(u2h2(xv[q].y), u2h2(wi0A[4*q+1]), gA1);
                    gA0 = fdot2(u2h2(xv[q].z), u2h2(wi0A[4*q+2]), gA0);
                    gA1 = fdot2(u2h2(xv[q].w), u2h2(wi0A[4*q+3]), gA1);
                    gB0 = fdot2(u2h2(xv[q].x), u2h2(wi0B[4*q+0]), gB0);
                    gB1 = fdot2(u2h2(xv[q].y), u2h2(wi0B[4*q+1]), gB1);
                    gB0 = fdot2(u2h2(xv[q].z), u2h2(wi0B[4*q+2]), gB0);
                    gB1 = fdot2(u2h2(xv[q].w), u2h2(wi0B[4*q+3]), gB1);
                }
                LDS_ORDER();
                dst[u][lane] = pk16(gA0 + gA1, gB0 + gB1);
                LDS_ORDER();
            }
        };

        // prologue: block 0 sync -> gxbuf[0]; issue block 1 loads
        float4 xr0 = reinterpret_cast<const float4*>(xrow + lane * 8)[0];
        float4 xr1 = reinterpret_cast<const float4*>(xrow + lane * 8 + 4)[0];
        VM_FENCE();
        stage(xr0, xr1);
        compute_block(gxbuf[0]);
        xr0 = reinterpret_cast<const float4*>(xrow + 512 + lane * 8)[0];
        xr1 = reinterpret_cast<const float4*>(xrow + 512 + lane * 8 + 4)[0];

        LGKM_FENCE();
        __builtin_amdgcn_s_barrier();     // prologue

        for (int s = 0; s < NSUPER; ++s) {
            VM_FENCE();                   // block min(s+1,63) landed
            stage(xr0, xr1);
            compute_block(gxbuf[(s + 1) & 1]);
            const int sn = (s + 2 < NSUPER) ? (s + 2) : (NSUPER - 1);
            xr0 = reinterpret_cast<const float4*>(xrow + sn * 512 + lane * 8)[0];
            xr1 = reinterpret_cast<const float4*>(xrow + sn * 512 + lane * 8 + 4)[0];
            LGKM_FENCE();
            __builtin_amdgcn_s_barrier();
        }
    }
}

extern "C" void kernel_launch(void* const* d_in, const int* in_sizes, int n_in,
                              void* d_out, int out_size, void* d_ws, size_t ws_size,
                              hipStream_t stream) {
    (void)in_sizes; (void)n_in; (void)out_size; (void)d_ws; (void)ws_size;
    const float* x    = (const float*)d_in[0];
    const float* Wih0 = (const float*)d_in[1];
    const float* Whh0 = (const float*)d_in[2];
    const float* bih0 = (const float*)d_in[3];
    const float* bhh0 = (const float*)d_in[4];
    const float* Wih1 = (const float*)d_in[5];
    const float* Whh1 = (const float*)d_in[6];
    const float* bih1 = (const float*)d_in[7];
    const float* bhh1 = (const float*)d_in[8];
    const float* Wfc  = (const float*)d_in[9];
    const float* bfc  = (const float*)d_in[10];
    float* out = (float*)d_out;

    hipLaunchKernelGGL(lstm_scan_kernel, dim3(B_SZ), dim3(192), 0, stream,
                       x, Wih0, Whh0, bih0, bhh0, Wih1, Whh1, bih1, bhh1,
                       Wfc, bfc, out);
}